// Round 8
// baseline (1696.058 us; speedup 1.0000x reference)
//
#include <hip/hip_runtime.h>

// LSTM, B=512 x T=1024, H=100, input_size=1.
// R12: per-batch-step cycles are ~invariant (R4 1450 / R10 1456 / R11 1280)
// across 2x instr, 2x occupancy, 44x conflicts => the wall is the per-step
// SERIAL SKELETON: 2 barriers + 2 LDS round-trips + exposed latency. Batch
// residency is pinned at 2/CU (512 batches / 256 CUs), so the only lever is
// shrinking the skeleton. This kernel: ONE barrier + ONE LDS hop per step.
//  - thread (u,ch): u=tid>>2 owns unit u's 4 gate rows {u,100+u,200+u,300+u},
//    ch=tid&3 owns k in [26ch,26ch+26) (h zero-padded to 104). 52 v2f
//    weights, pk_fma.
//  - quad-shuffle reduce: the 4 chunk partials of unit u sit in one quad ->
//    2 x shfl_xor stages; all 4 lanes redundantly run activations + cell
//    (c replicated); lane ch==0 writes h. NO partial LDS buffer, NO RB phase.
//  - h double-buffered by parity: read h[t&1], write h[(t&1)^1] -> a single
//    __syncthreads per step is race-free. hw (h*W_out) parity stash feeds a
//    lagged out-projection on wave 7 (concurrent, disjoint parity).
// BLOCK=512, grid=512 (1 batch/block, 2 blocks/CU as in R11).

#define HID   100
#define TLEN  1024
#define BLOCK 512
#define HPAD  112    // h buffer stride: 104 used (100 + 4 zero-pad), 8B-aligned

typedef float v2f __attribute__((ext_vector_type(2)));

// D = S0*S1 + D, two f32 lanes per instruction (CDNA packed fp32).
#define PKFMA(A, B, C) asm("v_pk_fma_f32 %0, %1, %2, %0" : "+v"(A) : "v"(B), "v"(C))

__global__ __launch_bounds__(BLOCK, 4)
void lstm_quad(
    const float* __restrict__ input,   // [B, T]
    const float* __restrict__ W_ih,    // [4H]
    const float* __restrict__ W_hh,    // [4H, H]
    const float* __restrict__ b_ih,    // [4H]
    const float* __restrict__ b_hh,    // [4H]
    const float* __restrict__ W_out,   // [H]
    const float* __restrict__ b_out,   // [1]
    float* __restrict__ out)           // [B, T]
{
    const int b    = blockIdx.x;
    const int tid  = threadIdx.x;
    const int lane = tid & 63;
    const int wave = tid >> 6;

    __shared__ float h_s[2][HPAD];     // parity-double-buffered h
    __shared__ float hw_s[2][128];     // parity h*W_out stash (pads 0)
    __shared__ float in_s[TLEN];
    __shared__ float wib_s[4 * HID];   // W_ih
    __shared__ float bib_s[4 * HID];   // b_ih + b_hh
    __shared__ float wo_s[128];        // W_out (100 used, pads 0)
    __shared__ float bo_s;

    // One-time staging.
    for (int i = tid; i < TLEN; i += BLOCK) in_s[i] = input[b * TLEN + i];
    if (tid < 4 * HID) { wib_s[tid] = W_ih[tid]; bib_s[tid] = b_ih[tid] + b_hh[tid]; }
    if (tid < 128) wo_s[tid] = (tid < HID) ? W_out[tid] : 0.f;
    if (tid < 224) ((float*)h_s)[tid] = 0.f;            // both parities + pads
    else if (tid < 480) ((float*)hw_s)[tid - 224] = 0.f; // both parities + pads
    if (tid == 0) bo_s = b_out[0];

    // ---- A role: tid<400. u = tid>>2 (unit), ch = tid&3 (k-chunk).
    const bool isA = (tid < 400);
    const int  u   = isA ? (tid >> 2) : 0;
    const int  ch  = tid & 3;
    const int  kb  = 26 * ch;
    v2f wq[4][13];                     // rows {u,100+u,200+u,300+u} x 26 k
    #pragma unroll
    for (int r = 0; r < 4; ++r) {
        const float* wr = W_hh + (r * HID + u) * HID;
        #pragma unroll
        for (int j = 0; j < 13; ++j) {
            const int k0 = kb + 2 * j, k1 = k0 + 1;
            v2f v;
            v.x = (k0 < HID) ? wr[k0] : 0.f;
            v.y = (k1 < HID) ? wr[k1] : 0.f;
            asm volatile("" : "+v"(v));    // pin: block remat/reload
            wq[r][j] = v;
        }
    }

    float c = 0.f;                     // cell state (replicated per quad)
    __syncthreads();

    #pragma unroll 1
    for (int t = 0; t < TLEN; ++t) {
        if (isA) {
            // ---- dot partials for this k-chunk (broadcast b64 h reads)
            const float* hp = h_s[t & 1] + kb;
            v2f ai = {0.f, 0.f}, af = {0.f, 0.f};
            v2f ag = {0.f, 0.f}, ao = {0.f, 0.f};
            #pragma unroll
            for (int j = 0; j < 13; ++j) {
                v2f hv = *(const v2f*)(hp + 2 * j);   // 4 addrs/wave: bcast
                PKFMA(ai, hv, wq[0][j]);
                PKFMA(af, hv, wq[1][j]);
                PKFMA(ag, hv, wq[2][j]);
                PKFMA(ao, hv, wq[3][j]);
                if (j == 5 || j == 9) __builtin_amdgcn_sched_barrier(0);
            }
            float pi = ai.x + ai.y, pf = af.x + af.y;
            float pg = ag.x + ag.y, po = ao.x + ao.y;
            // ---- quad butterfly: all 4 lanes get full 100-k sums
            pi += __shfl_xor(pi, 1); pf += __shfl_xor(pf, 1);
            pg += __shfl_xor(pg, 1); po += __shfl_xor(po, 1);
            pi += __shfl_xor(pi, 2); pf += __shfl_xor(pf, 2);
            pg += __shfl_xor(pg, 2); po += __shfl_xor(po, 2);
            // ---- x-proj + activations + cell (redundant across the quad)
            const float x = in_s[t];
            float ig = fmaf(x, wib_s[u],           bib_s[u])           + pi;
            float fg = fmaf(x, wib_s[HID + u],     bib_s[HID + u])     + pf;
            float gg = fmaf(x, wib_s[2 * HID + u], bib_s[2 * HID + u]) + pg;
            float og = fmaf(x, wib_s[3 * HID + u], bib_s[3 * HID + u]) + po;
            float is = __builtin_amdgcn_rcpf(1.f + __expf(-ig));
            float fs = __builtin_amdgcn_rcpf(1.f + __expf(-fg));
            float os = __builtin_amdgcn_rcpf(1.f + __expf(-og));
            float gt = 1.f - 2.f * __builtin_amdgcn_rcpf(__expf(2.f * gg) + 1.f);
            c = fmaf(fs, c, is * gt);
            float th = 1.f - 2.f * __builtin_amdgcn_rcpf(__expf(2.f * c) + 1.f);
            float hn = os * th;
            if ((tid & 3) == 0) {
                h_s[(t & 1) ^ 1][u] = hn;          // next-parity h
                hw_s[t & 1][u]      = hn * wo_s[u]; // this step's out stash
            }
        } else if (wave == 7) {
            // ---- lagged out-projection: out[b, t-1] from hw(t-1).
            // Reads parity (t-1)&1 while writers fill t&1: disjoint.
            if (t > 0) {
                const float* hw = hw_s[(t - 1) & 1];
                float v = hw[lane] + hw[64 + lane];   // pads are 0
                #pragma unroll
                for (int off = 32; off > 0; off >>= 1)
                    v += __shfl_down(v, off);
                if (lane == 0) out[b * TLEN + (t - 1)] = v + bo_s;
            }
        }
        __syncthreads();   // the ONLY barrier per step
    }

    // Final column t = TLEN-1.
    if (wave == 7) {
        const float* hw = hw_s[(TLEN - 1) & 1];
        float v = hw[lane] + hw[64 + lane];
        #pragma unroll
        for (int off = 32; off > 0; off >>= 1)
            v += __shfl_down(v, off);
        if (lane == 0) out[b * TLEN + (TLEN - 1)] = v + bo_s;
    }
}

extern "C" void kernel_launch(void* const* d_in, const int* in_sizes, int n_in,
                              void* d_out, int out_size, void* d_ws, size_t ws_size,
                              hipStream_t stream) {
    const float* input = (const float*)d_in[0];
    const float* W_ih  = (const float*)d_in[1];
    const float* W_hh  = (const float*)d_in[2];
    const float* b_ih  = (const float*)d_in[3];
    const float* b_hh  = (const float*)d_in[4];
    const float* W_out = (const float*)d_in[5];
    const float* b_out = (const float*)d_in[6];
    float* out = (float*)d_out;

    const int B = in_sizes[0] / TLEN;  // 512
    lstm_quad<<<B, BLOCK, 0, stream>>>(input, W_ih, W_hh, b_ih, b_hh,
                                       W_out, b_out, out);
}

// Round 9
// 1102.004 us; speedup vs baseline: 1.5391x; 1.5391x over previous
//
#include <hip/hip_runtime.h>

// LSTM, B=512 x T=1024, H=100, input_size=1.
// R13: R12's WRITE_SIZE=13MB proved 104 floats/thread = scratch spill (1-
// barrier skeleton untested). FETCH decode of earlier rounds: R10 (no pin,
// FETCH 3.2MB, hbm 16GB/s) was RELOADING weights every step; R11 (pin,
// FETCH 1.7MB) was resident but ~136 regs -> no co-resident 2nd block
// (occ 41%). Never yet combined: residency + co-residency + pk_fma.
// This kernel = R10 structure (R=2,K=20 -> 40 weight floats, the smallest
// footprint of any round) + R11's asm pin + pk_fma + launch_bounds(1024,8)
// (16-wave block, 2 blocks/CU = 8 waves/SIMD, 64-reg budget; estimate
// 40 pinned + ~21 working = 61). Second co-resident block fills the
// ~600cyc/step serial chain (LDS round trips + exp chain + barriers).
// Falsifiers: occ>=85 (co-residency), FETCH~1.7MB (pin), WRITE~2MB (no
// spill). If all hold and dur ~1000us: per-batch-step wall is structural.

#define HID   100
#define TLEN  1024
#define BLOCK 1024
#define NROW  400
#define PCH   402            // partial row stride in floats (= 201 float2)

typedef float v2f __attribute__((ext_vector_type(2)));
typedef float v4f __attribute__((ext_vector_type(4)));

// D = S0*S1 + D, two f32 lanes per instruction (CDNA packed fp32).
#define PKFMA(A, B, C) asm("v_pk_fma_f32 %0, %1, %2, %0" : "+v"(A) : "v"(B), "v"(C))

__global__ __launch_bounds__(BLOCK, 8)
void lstm_copk(
    const float* __restrict__ input,   // [B, T]
    const float* __restrict__ W_ih,    // [4H]
    const float* __restrict__ W_hh,    // [4H, H]
    const float* __restrict__ b_ih,    // [4H]
    const float* __restrict__ b_hh,    // [4H]
    const float* __restrict__ W_out,   // [H]
    const float* __restrict__ b_out,   // [1]
    float* __restrict__ out)           // [B, T]
{
    const int b    = blockIdx.x;
    const int tid  = threadIdx.x;
    const int lane = tid & 63;
    const int wave = tid >> 6;

    __shared__ v4f   h4_s[32];          // h: 128 floats (0..99 used)
    __shared__ float2 part2_s[5 * 201]; // partials, 8-byte aligned
    __shared__ float hw_s[2 * 128];     // parity-buffered h*W_out
    __shared__ float in_s[TLEN];
    __shared__ float wib_s[NROW];       // W_ih
    __shared__ float bib_s[NROW];       // b_ih + b_hh
    __shared__ float wo_s[128];         // W_out (100 used, pads 0)
    __shared__ float bo_s;

    float*       h_s    = (float*)h4_s;
    const float* part_s = (const float*)part2_s;

    // One-time staging (coalesced / tiny).
    for (int i = tid; i < TLEN; i += BLOCK) in_s[i] = input[b * TLEN + i];
    if (tid < NROW) { wib_s[tid] = W_ih[tid]; bib_s[tid] = b_ih[tid] + b_hh[tid]; }
    if (tid >= 512 && tid < 640) wo_s[tid - 512] = (tid - 512 < HID) ? W_out[tid - 512] : 0.f;
    if (tid == BLOCK - 1) bo_s = b_out[0];
    if (tid < 128) h_s[tid] = 0.f;

    // ---- A role: tid<1000. pair p = tid%200 (rows 2p,2p+1), ch = tid/200
    // (k in [20ch, 20ch+20)). 40 weight floats as 2x10 v2f, PINNED.
    const bool isA = (tid < 1000);
    const int  p   = isA ? (tid % 200) : 0;
    const int  ch  = isA ? (tid / 200) : 0;
    v2f w2a[10], w2b[10];
    {
        const v2f* wr0 = (const v2f*)(W_hh + (2 * p) * HID + 20 * ch);
        const v2f* wr1 = (const v2f*)(W_hh + (2 * p + 1) * HID + 20 * ch);
        #pragma unroll
        for (int j = 0; j < 10; ++j) {
            v2f va = wr0[j], vb = wr1[j];
            asm volatile("" : "+v"(va));   // pin: block remat/reload (R10 bug)
            asm volatile("" : "+v"(vb));
            w2a[j] = va; w2b[j] = vb;
        }
    }

    float c = 0.f;                         // cell state (tid<100 only)
    __syncthreads();

    #pragma unroll 1
    for (int t = 0; t < TLEN; ++t) {
        // ---- Phase A: 2-row x 20-k packed dot partials.
        if (isA) {
            const v4f* hp = (const v4f*)h4_s + 5 * ch;
            v2f a0 = {0.f, 0.f}, a1 = {0.f, 0.f};
            #pragma unroll
            for (int jj = 0; jj < 5; ++jj) {
                v4f hv = hp[jj];           // one addr per ~wave: broadcast
                v2f hlo = __builtin_shufflevector(hv, hv, 0, 1);
                v2f hhi = __builtin_shufflevector(hv, hv, 2, 3);
                PKFMA(a0, hlo, w2a[2 * jj]); PKFMA(a0, hhi, w2a[2 * jj + 1]);
                PKFMA(a1, hlo, w2b[2 * jj]); PKFMA(a1, hhi, w2b[2 * jj + 1]);
                // cap in-flight h reads so peak regs stay <= 64
                if (jj == 1 || jj == 3) __builtin_amdgcn_sched_barrier(0);
            }
            float2 pr; pr.x = a0.x + a0.y; pr.y = a1.x + a1.y;
            part2_s[ch * 201 + p] = pr;    // rows 2p,2p+1 of chunk ch
        }
        __syncthreads();

        // ---- Phase RB: reduce 5 chunks x 4 gates + cell update (100 thr).
        if (tid < HID) {
            const float* pp = part_s + tid;
            float s0 = ((pp[0]   + pp[PCH])   + (pp[2*PCH]   + pp[3*PCH]))   + pp[4*PCH];
            const float* q1 = pp + 100;
            float s1 = ((q1[0]   + q1[PCH])   + (q1[2*PCH]   + q1[3*PCH]))   + q1[4*PCH];
            const float* q2 = pp + 200;
            float s2 = ((q2[0]   + q2[PCH])   + (q2[2*PCH]   + q2[3*PCH]))   + q2[4*PCH];
            const float* q3 = pp + 300;
            float s3 = ((q3[0]   + q3[PCH])   + (q3[2*PCH]   + q3[3*PCH]))   + q3[4*PCH];
            const float x = in_s[t];
            float ig = fmaf(x, wib_s[tid],       bib_s[tid])       + s0;
            float fg = fmaf(x, wib_s[100 + tid], bib_s[100 + tid]) + s1;
            float gg = fmaf(x, wib_s[200 + tid], bib_s[200 + tid]) + s2;
            float og = fmaf(x, wib_s[300 + tid], bib_s[300 + tid]) + s3;
            float is = __builtin_amdgcn_rcpf(1.f + __expf(-ig));
            float fs = __builtin_amdgcn_rcpf(1.f + __expf(-fg));
            float os = __builtin_amdgcn_rcpf(1.f + __expf(-og));
            float gt = 1.f - 2.f * __builtin_amdgcn_rcpf(__expf(2.f * gg) + 1.f);
            c = fmaf(fs, c, is * gt);
            float th = 1.f - 2.f * __builtin_amdgcn_rcpf(__expf(2.f * c) + 1.f);
            float hn = os * th;
            h_s[tid] = hn;
            hw_s[(t & 1) * 128 + tid] = hn * wo_s[tid];   // stash h*W_out
        } else if (wave == 2) {
            // ---- Phase C (lagged 1 step): out[b,t-1] = sum(hw(t-1)) + bo.
            // Reads parity (t-1)&1 while RB writes (t&1): disjoint.
            if (t > 0) {
                const float* hw = hw_s + ((t - 1) & 1) * 128;
                const int l = tid - 128;
                float v = hw[l] + ((l < HID - 64) ? hw[64 + l] : 0.f);
                #pragma unroll
                for (int off = 32; off > 0; off >>= 1)
                    v += __shfl_down(v, off);
                if (l == 0) out[b * TLEN + (t - 1)] = v + bo_s;
            }
        }
        __syncthreads();
    }

    // Final column t = TLEN-1 (hw parity (TLEN-1)&1, stable after last barrier)
    if (wave == 2) {
        const float* hw = hw_s + ((TLEN - 1) & 1) * 128;
        const int l = tid - 128;
        float v = hw[l] + ((l < HID - 64) ? hw[64 + l] : 0.f);
        #pragma unroll
        for (int off = 32; off > 0; off >>= 1)
            v += __shfl_down(v, off);
        if (l == 0) out[b * TLEN + (TLEN - 1)] = v + bo_s;
    }
}

extern "C" void kernel_launch(void* const* d_in, const int* in_sizes, int n_in,
                              void* d_out, int out_size, void* d_ws, size_t ws_size,
                              hipStream_t stream) {
    const float* input = (const float*)d_in[0];
    const float* W_ih  = (const float*)d_in[1];
    const float* W_hh  = (const float*)d_in[2];
    const float* b_ih  = (const float*)d_in[3];
    const float* b_hh  = (const float*)d_in[4];
    const float* W_out = (const float*)d_in[5];
    const float* b_out = (const float*)d_in[6];
    float* out = (float*)d_out;

    const int B = in_sizes[0] / TLEN;  // 512
    lstm_copk<<<B, BLOCK, 0, stream>>>(input, W_ih, W_hh, b_ih, b_hh,
                                       W_out, b_out, out);
}

// Round 10
// 965.984 us; speedup vs baseline: 1.7558x; 1.1408x over previous
//
#include <hip/hip_runtime.h>

// LSTM, B=512 x T=1024, H=100, input_size=1.
// R14 = R11 verbatim with ONE change: __launch_bounds__(512, 2) (min 2
// waves/EU -> 256-VGPR budget, was 4 -> 128).
// Rationale: R11's measured VALU issue = 1285 cyc/SIMD/step = ~160
// instr/wave/step vs ~75 in the source. The missing ~80 = one
// v_accvgpr_read per pinned weight per step: at VGPR_Count=56 the 80
// weight floats live in AGPRs (unified file) and every use pays a move.
// The allocator never used the 128 budget in ANY round (arch 32-60 always).
// Hypothesis: budget starvation -> AGPR parking. At 256 budget, weights
// (80) + working (~35) = ~115 fits arch comfortably; if allocation lands
// <=128 the 2-block/CU co-residency survives too.
// Outcomes: VGPR 100-128 -> tax dead, expect ~600-750us. VGPR >128 ->
// occupancy halves (bounded loss). VGPR ~56 -> AGPR parking is policy,
// falsifies budget theory.

#define HID   100
#define TLEN  1024
#define BLOCK 512

typedef float v2f __attribute__((ext_vector_type(2)));
typedef float v4f __attribute__((ext_vector_type(4)));

// D = S0*S1 + D, two f32 lanes per instruction (CDNA packed fp32).
#define PKFMA(A, B, C) asm("v_pk_fma_f32 %0, %1, %2, %0" : "+v"(A) : "v"(B), "v"(C))

__global__ __launch_bounds__(BLOCK, 2)
void lstm_pk256(
    const float* __restrict__ input,   // [B, T]
    const float* __restrict__ W_ih,    // [4H]
    const float* __restrict__ W_hh,    // [4H, H]
    const float* __restrict__ b_ih,    // [4H]
    const float* __restrict__ b_hh,    // [4H]
    const float* __restrict__ W_out,   // [H]
    const float* __restrict__ b_out,   // [1]
    float* __restrict__ out)           // [B, T]
{
    const int b    = blockIdx.x;
    const int tid  = threadIdx.x;
    const int lane = tid & 63;
    const int wave = tid >> 6;

    __shared__ v4f   h4_s[32];          // h: 128 floats (0..99 used, pad 0)
    __shared__ v4f   part4_s[505];      // partials: [5 chunks][404 floats]
    __shared__ float hw_s[2 * 128];     // parity-buffered h*W_out
    __shared__ float in_s[TLEN];
    __shared__ float wib_s[4 * HID];    // W_ih
    __shared__ float bib_s[4 * HID];    // b_ih + b_hh
    __shared__ float wo_s[128];         // W_out (100 used)
    __shared__ float bo_s;

    float* h_s = (float*)h4_s;

    // One-time staging.
    for (int i = tid; i < TLEN; i += BLOCK) in_s[i] = input[b * TLEN + i];
    if (tid < 4 * HID) { wib_s[tid] = W_ih[tid]; bib_s[tid] = b_ih[tid] + b_hh[tid]; }
    if (tid < 128) { h_s[tid] = 0.f; wo_s[tid] = (tid < HID) ? W_out[tid] : 0.f; }
    if (tid == 0) bo_s = b_out[0];

    // ---- A role: tid<500. g = tid%100 (rows 4g..4g+3), ch = tid/100
    // (k in [20ch, 20ch+20)). Weights: 4 rows x 10 v2f = 80 VGPRs.
    const bool isA = (tid < 500);
    const int  g   = isA ? (tid % 100) : 0;
    const int  ch  = isA ? (tid / 100) : 0;
    v2f w2[4][10];
    #pragma unroll
    for (int r = 0; r < 4; ++r) {
        const v2f* wr = (const v2f*)(W_hh + (4 * g + r) * HID + 20 * ch);
        #pragma unroll
        for (int j = 0; j < 10; ++j) {
            v2f v = wr[j];
            asm volatile("" : "+v"(v));   // pin: block remat of the load
            w2[r][j] = v;
        }
    }

    float c = 0.f;                        // cell state (tid<100 only)
    __syncthreads();

    #pragma unroll 1
    for (int t = 0; t < TLEN; ++t) {
        // ---- Phase A: 4-row x 20-k packed dot partials.
        {
            const v4f* hp = (const v4f*)h4_s + 5 * ch;
            v2f a0 = {0.f, 0.f}, a1 = {0.f, 0.f};
            v2f a2 = {0.f, 0.f}, a3 = {0.f, 0.f};
            #pragma unroll
            for (int jj = 0; jj < 5; ++jj) {
                v4f hv = hp[jj];           // <=2 distinct addrs/wave: bcast
                v2f hlo = __builtin_shufflevector(hv, hv, 0, 1);
                v2f hhi = __builtin_shufflevector(hv, hv, 2, 3);
                PKFMA(a0, hlo, w2[0][2 * jj]); PKFMA(a0, hhi, w2[0][2 * jj + 1]);
                PKFMA(a1, hlo, w2[1][2 * jj]); PKFMA(a1, hhi, w2[1][2 * jj + 1]);
                PKFMA(a2, hlo, w2[2][2 * jj]); PKFMA(a2, hhi, w2[2][2 * jj + 1]);
                PKFMA(a3, hlo, w2[3][2 * jj]); PKFMA(a3, hhi, w2[3][2 * jj + 1]);
            }
            if (isA) {
                v4f pr;
                pr.x = a0.x + a0.y; pr.y = a1.x + a1.y;
                pr.z = a2.x + a2.y; pr.w = a3.x + a3.y;
                part4_s[101 * ch + g] = pr;   // rows 4g..4g+3 of chunk ch
            }
        }
        __syncthreads();

        // ---- Phase RB: reduce 5 chunks x 4 gates + cell update (100 thr).
        if (tid < HID) {
            const float* ps = (const float*)part4_s;
            float s0 = 0.f, s1 = 0.f, s2 = 0.f, s3 = 0.f;
            #pragma unroll
            for (int cc = 0; cc < 5; ++cc) {
                const float* pp = ps + 404 * cc + tid;   // row = gate*100+tid
                s0 += pp[0];
                s1 += pp[100];
                s2 += pp[200];
                s3 += pp[300];
            }
            const float x = in_s[t];
            float ig = fmaf(x, wib_s[tid],           bib_s[tid])           + s0;
            float fg = fmaf(x, wib_s[HID + tid],     bib_s[HID + tid])     + s1;
            float gg = fmaf(x, wib_s[2 * HID + tid], bib_s[2 * HID + tid]) + s2;
            float og = fmaf(x, wib_s[3 * HID + tid], bib_s[3 * HID + tid]) + s3;
            float is = __builtin_amdgcn_rcpf(1.f + __expf(-ig));
            float fs = __builtin_amdgcn_rcpf(1.f + __expf(-fg));
            float os = __builtin_amdgcn_rcpf(1.f + __expf(-og));
            float gt = 1.f - 2.f * __builtin_amdgcn_rcpf(__expf(2.f * gg) + 1.f);
            c = fmaf(fs, c, is * gt);
            float th = 1.f - 2.f * __builtin_amdgcn_rcpf(__expf(2.f * c) + 1.f);
            float hn = os * th;
            h_s[tid] = hn;
            hw_s[(t & 1) * 128 + tid] = hn * wo_s[tid];  // stash h*W_out
        } else if (wave == 2) {
            // ---- Phase C (lagged 1 step): out[b,t-1] = sum(hw(t-1)) + bo.
            if (t > 0) {
                const float* hw = hw_s + ((t - 1) & 1) * 128;
                float v = hw[lane] + ((lane < HID - 64) ? hw[64 + lane] : 0.f);
                #pragma unroll
                for (int off = 32; off > 0; off >>= 1)
                    v += __shfl_down(v, off);
                if (lane == 0) out[b * TLEN + (t - 1)] = v + bo_s;
            }
        }
        __syncthreads();
    }

    // Final column t = TLEN-1.
    if (wave == 2) {
        const float* hw = hw_s + ((TLEN - 1) & 1) * 128;
        float v = hw[lane] + ((lane < HID - 64) ? hw[64 + lane] : 0.f);
        #pragma unroll
        for (int off = 32; off > 0; off >>= 1)
            v += __shfl_down(v, off);
        if (lane == 0) out[b * TLEN + (TLEN - 1)] = v + bo_s;
    }
}

extern "C" void kernel_launch(void* const* d_in, const int* in_sizes, int n_in,
                              void* d_out, int out_size, void* d_ws, size_t ws_size,
                              hipStream_t stream) {
    const float* input = (const float*)d_in[0];
    const float* W_ih  = (const float*)d_in[1];
    const float* W_hh  = (const float*)d_in[2];
    const float* b_ih  = (const float*)d_in[3];
    const float* b_hh  = (const float*)d_in[4];
    const float* W_out = (const float*)d_in[5];
    const float* b_out = (const float*)d_in[6];
    float* out = (float*)d_out;

    const int B = in_sizes[0] / TLEN;  // 512
    lstm_pk256<<<B, BLOCK, 0, stream>>>(input, W_ih, W_hh, b_ih, b_hh,
                                        W_out, b_out, out);
}